// Round 1
// baseline (832.060 us; speedup 1.0000x reference)
//
#include <hip/hip_runtime.h>

#define FD 96   // feature dim

// ---------------------------------------------------------------------------
// K1: degree histogram over dst. Hub (dst==HUB) handled via ballot+popcount
// to avoid ~50k serialized atomics on one address.
// ---------------------------------------------------------------------------
__global__ void deg_kernel(const int* __restrict__ dst, int E, int HUB,
                           float* __restrict__ deg) {
    int e = blockIdx.x * blockDim.x + threadIdx.x;
    int d = -1;
    if (e < E) d = dst[e];
    bool isHub = (d == HUB);
    unsigned long long m = __ballot(isHub);
    if (isHub) {
        int lane = threadIdx.x & 63;
        int leader = __ffsll((unsigned long long)m) - 1;
        if (lane == leader) {
            unsafeAtomicAdd(&deg[HUB], (float)__popcll(m));
        }
    } else if (d >= 0) {
        unsafeAtomicAdd(&deg[d], 1.0f);
    }
}

// ---------------------------------------------------------------------------
// K2: dinv = deg>0 ? rsqrt(max(deg,1)) : 0
// ---------------------------------------------------------------------------
__global__ void dinv_kernel(const float* __restrict__ deg, float* __restrict__ dinv,
                            int N) {
    int n = blockIdx.x * blockDim.x + threadIdx.x;
    if (n < N) {
        float d = deg[n];
        dinv[n] = (d > 0.f) ? rsqrtf(fmaxf(d, 1.f)) : 0.f;
    }
}

// ---------------------------------------------------------------------------
// K3: aggregation out[dst] += h[src] * dinv[src]*dinv[dst]  (scatter-atomic)
// blockDim = (96,2). Block handles EB=128 contiguous edges. Thread owns a
// fixed feature f; hub contributions accumulate in a register, reduced via
// LDS, 96 atomics per block instead of 96*edges.
// ---------------------------------------------------------------------------
#define EB 128
__global__ __launch_bounds__(192)
void agg_kernel(const float* __restrict__ h, const float* __restrict__ dinv,
                const int* __restrict__ src, const int* __restrict__ dst,
                int E, int HUB, float* __restrict__ out) {
    int f    = threadIdx.x;   // 0..95
    int pair = threadIdx.y;   // 0..1
    long e0 = (long)blockIdx.x * EB;
    float hubacc = 0.f;
    for (int i = pair; i < EB; i += 2) {
        long e = e0 + i;
        if (e >= E) break;
        int s = src[e];
        int d = dst[e];
        float w = dinv[s] * dinv[d];
        float v = h[(long)s * FD + f] * w;
        if (d == HUB) {
            hubacc += v;
        } else {
            unsafeAtomicAdd(&out[(long)d * FD + f], v);
        }
    }
    __shared__ float lds[2 * FD];
    lds[pair * FD + f] = hubacc;
    __syncthreads();
    if (pair == 0) {
        float v = lds[f] + lds[FD + f];
        if (v != 0.f) unsafeAtomicAdd(&out[(long)HUB * FD + f], v);
    }
}

// ---------------------------------------------------------------------------
// K4: out[N,96] = A[N,96] @ W[96,96] (+ bias) (optional relu)
// W staged in LDS (36 KB), 16 A-rows staged in LDS, thread = (col f, y),
// computes 8 rows. k unrolled by 4 with float4 LDS reads of A.
// ---------------------------------------------------------------------------
__global__ __launch_bounds__(192)
void gemm96(const float* __restrict__ A, const float* __restrict__ W,
            const float* __restrict__ bias, float* __restrict__ out,
            int N, int relu) {
    __shared__ float Wl[FD * FD];      // 36 KB
    __shared__ float As[16 * FD];      // 6 KB
    int t = threadIdx.x + threadIdx.y * FD;   // 0..191

    // stage W (float4 coalesced)
    const float4* W4 = (const float4*)W;
    float4* Wl4 = (float4*)Wl;
    for (int i = t; i < FD * FD / 4; i += 192) Wl4[i] = W4[i];

    int row0 = blockIdx.x * 16;
    int nrows = min(16, N - row0);
    const float4* A4 = (const float4*)(A + (long)row0 * FD);
    float4* As4 = (float4*)As;
    for (int i = t; i < nrows * (FD / 4); i += 192) As4[i] = A4[i];
    __syncthreads();

    int f = threadIdx.x;   // column
    int y = threadIdx.y;
    float acc[8];
#pragma unroll
    for (int j = 0; j < 8; j++) acc[j] = 0.f;

    for (int k = 0; k < FD; k += 4) {
        float w0 = Wl[(k + 0) * FD + f];
        float w1 = Wl[(k + 1) * FD + f];
        float w2 = Wl[(k + 2) * FD + f];
        float w3 = Wl[(k + 3) * FD + f];
#pragma unroll
        for (int j = 0; j < 8; j++) {
            const float4 a = *(const float4*)&As[(y + 2 * j) * FD + k];
            acc[j] = fmaf(a.x, w0, fmaf(a.y, w1, fmaf(a.z, w2, fmaf(a.w, w3, acc[j]))));
        }
    }

    float b = bias ? bias[f] : 0.f;
#pragma unroll
    for (int j = 0; j < 8; j++) {
        int r = y + 2 * j;
        if (row0 + r < N) {
            float v = acc[j] + b;
            if (relu) v = fmaxf(v, 0.f);
            out[(long)(row0 + r) * FD + f] = v;
        }
    }
}

// ---------------------------------------------------------------------------
// Launch. Pipeline (linear-algebra reassociated: (A@X)@W == A@(X@W)):
//   a0 = A@x          -> stored in d_out[mu region]   (dead before mu write)
//   h1 = relu(a0@W1+b1) -> stored in d_out[logstd region] (dead before write)
//   a1 = A@h1         -> ws
//   mu = a1@W2a+b2a; logstd = a1@W2b+b2b
// ---------------------------------------------------------------------------
extern "C" void kernel_launch(void* const* d_in, const int* in_sizes, int n_in,
                              void* d_out, int out_size, void* d_ws, size_t ws_size,
                              hipStream_t stream) {
    const float* x   = (const float*)d_in[0];
    const float* W1  = (const float*)d_in[1];
    const float* b1  = (const float*)d_in[2];
    const float* W2a = (const float*)d_in[3];
    const float* b2a = (const float*)d_in[4];
    const float* W2b = (const float*)d_in[5];
    const float* b2b = (const float*)d_in[6];
    const int*   ei  = (const int*)d_in[7];

    const int N   = in_sizes[0] / FD;
    const int E   = in_sizes[7] / 2;
    const int HUB = N - 1;
    const int* src = ei;
    const int* dst = ei + E;

    // workspace: [deg N][a1 N*96][dinv N]  (~19.6 MB)
    float* ws   = (float*)d_ws;
    float* deg  = ws;
    float* a1   = ws + N;
    float* dinv = a1 + (size_t)N * FD;

    float* mu = (float*)d_out;                      // also a0 scratch
    float* ls = (float*)d_out + (size_t)N * FD;     // also h1 scratch
    float* a0 = mu;
    float* h1 = ls;

    // zero-init accumulators (deg + a1 contiguous; a0 in d_out)
    hipMemsetAsync(deg, 0, (size_t)(N + (size_t)N * FD) * sizeof(float), stream);
    hipMemsetAsync(a0,  0, (size_t)N * FD * sizeof(float), stream);

    deg_kernel<<<dim3((E + 255) / 256), dim3(256), 0, stream>>>(dst, E, HUB, deg);
    dinv_kernel<<<dim3((N + 255) / 256), dim3(256), 0, stream>>>(deg, dinv, N);

    dim3 aggB(FD, 2);
    int aggG = (E + EB - 1) / EB;
    int gemmG = (N + 15) / 16;

    // layer 1
    agg_kernel<<<dim3(aggG), aggB, 0, stream>>>(x, dinv, src, dst, E, HUB, a0);
    gemm96<<<dim3(gemmG), aggB, 0, stream>>>(a0, W1, b1, h1, N, 1);

    // layer 2 (shared aggregation for mu and logstd)
    agg_kernel<<<dim3(aggG), aggB, 0, stream>>>(h1, dinv, src, dst, E, HUB, a1);
    gemm96<<<dim3(gemmG), aggB, 0, stream>>>(a1, W2a, b2a, mu, N, 0);
    gemm96<<<dim3(gemmG), aggB, 0, stream>>>(a1, W2b, b2b, ls, N, 0);
}

// Round 4
// 746.529 us; speedup vs baseline: 1.1146x; 1.1146x over previous
//
#include <hip/hip_runtime.h>

#define FD 96   // feature dim

// ---------------------------------------------------------------------------
// K1: degree histogram (int counts). Hub handled via ballot+popcount to avoid
// ~50k serialized atomics on one address.
// ---------------------------------------------------------------------------
__global__ void deg_kernel(const int* __restrict__ dst, int E, int HUB,
                           int* __restrict__ counts) {
    int e = blockIdx.x * 256 + threadIdx.x;
    int d = (e < E) ? dst[e] : -1;
    bool isHub = (d == HUB);
    unsigned long long m = __ballot(isHub);
    if (isHub) {
        int lane = threadIdx.x & 63;
        if (lane == __ffsll((unsigned long long)m) - 1)
            atomicAdd(&counts[HUB], (int)__popcll(m));
    } else if (d >= 0) {
        atomicAdd(&counts[d], 1);
    }
}

// ---------------------------------------------------------------------------
// K2: exclusive prefix sum of counts -> rowptr[N+1]. Single block, 1024
// threads, wave-shuffle scan + cross-wave LDS. ~49 chunks for N=50000.
// ---------------------------------------------------------------------------
__global__ __launch_bounds__(1024)
void scan_kernel(const int* __restrict__ counts, int* __restrict__ rowptr, int N) {
    const int T = 1024;
    int lane = threadIdx.x & 63;
    int wv   = threadIdx.x >> 6;      // 0..15
    __shared__ int wsum[16];
    __shared__ int carry_s;
    if (threadIdx.x == 0) carry_s = 0;
    __syncthreads();
    for (int base = 0; base < N; base += T) {
        int i = base + threadIdx.x;
        int v = (i < N) ? counts[i] : 0;
        int x = v;
        #pragma unroll
        for (int off = 1; off < 64; off <<= 1) {
            int t = __shfl_up(x, off);
            if (lane >= off) x += t;
        }
        if (lane == 63) wsum[wv] = x;
        __syncthreads();
        if (wv == 0 && lane < 16) {
            int w = wsum[lane];
            #pragma unroll
            for (int off = 1; off < 16; off <<= 1) {
                int t = __shfl_up(w, off);
                if (lane >= off) w += t;
            }
            wsum[lane] = w;                    // inclusive wave sums
        }
        __syncthreads();
        int waveoff = (wv == 0) ? 0 : wsum[wv - 1];
        int carry = carry_s;
        int incl = carry + waveoff + x;
        if (i < N) rowptr[i] = incl - v;       // exclusive
        __syncthreads();
        if (threadIdx.x == T - 1) carry_s = incl;
        __syncthreads();
    }
    if (threadIdx.x == 0) rowptr[N] = carry_s;
}

// ---------------------------------------------------------------------------
// K3: fill CSR col[] (src ids per dst row). Hub cursor via wave-aggregated
// atomic (one atomicAdd of popcount per wave) to avoid serialization.
// ---------------------------------------------------------------------------
__global__ void fill_kernel(const int* __restrict__ src, const int* __restrict__ dst,
                            int E, int HUB, const int* __restrict__ rowptr,
                            int* __restrict__ cursor, int* __restrict__ col) {
    int e = blockIdx.x * 256 + threadIdx.x;
    if (e >= E) return;
    int d = dst[e];
    bool isHub = (d == HUB);
    unsigned long long m = __ballot(isHub);
    int pos;
    if (isHub) {
        int lane = threadIdx.x & 63;
        int leader = __ffsll((unsigned long long)m) - 1;
        int base = 0;
        if (lane == leader) base = atomicAdd(&cursor[HUB], (int)__popcll(m));
        base = __shfl(base, leader);
        unsigned long long below = m & ((1ull << lane) - 1ull);
        pos = base + (int)__popcll(below);
    } else {
        pos = atomicAdd(&cursor[d], 1);
    }
    col[rowptr[d] + pos] = src[e];
}

// ---------------------------------------------------------------------------
// K4: dinv from int counts
// ---------------------------------------------------------------------------
__global__ void dinv_kernel(const int* __restrict__ counts, float* __restrict__ dinv,
                            int N) {
    int n = blockIdx.x * 256 + threadIdx.x;
    if (n < N) {
        float d = (float)counts[n];
        dinv[n] = (d > 0.f) ? rsqrtf(fmaxf(d, 1.f)) : 0.f;
    }
}

// ---------------------------------------------------------------------------
// K5: pull aggregation (light rows): out[n] = dinv[n] * sum_e dinv[s]*h[s].
// block (96,4): thread f owns feature f of node n. NO atomics, pure writes.
// Hub row is zeroed here (accumulated by hub_kernel next).
// ---------------------------------------------------------------------------
__global__ __launch_bounds__(384)
void pull_kernel(const float* __restrict__ h, const float* __restrict__ dinv,
                 const int* __restrict__ rowptr, const int* __restrict__ col,
                 int N, int HUB, float* __restrict__ out) {
    int f = threadIdx.x;                       // 0..95
    int n = blockIdx.x * 4 + threadIdx.y;
    if (n >= N) return;
    if (n == HUB) { out[(long)n * FD + f] = 0.f; return; }
    int beg = rowptr[n], end = rowptr[n + 1];
    float dn = dinv[n];
    float acc = 0.f;
    for (int e = beg; e < end; e++) {
        int s = col[e];                        // broadcast load across f
        acc += dinv[s] * h[(long)s * FD + f];  // coalesced 384B row gather
    }
    out[(long)n * FD + f] = acc * dn;
}

// ---------------------------------------------------------------------------
// K6: hub row (deg ~50016): grid-strided partial sums, LDS reduce, 96
// atomics per block into the (pre-zeroed) hub row.
// ---------------------------------------------------------------------------
__global__ __launch_bounds__(192)
void hub_kernel(const float* __restrict__ h, const float* __restrict__ dinv,
                const int* __restrict__ rowptr, const int* __restrict__ col,
                int HUB, float* __restrict__ out) {
    int f = threadIdx.x;   // 0..95
    int y = threadIdx.y;   // 0..1
    int beg = rowptr[HUB], end = rowptr[HUB + 1];
    float acc = 0.f;
    int stride = gridDim.x * 2;
    for (int e = beg + blockIdx.x * 2 + y; e < end; e += stride) {
        int s = col[e];
        acc += dinv[s] * h[(long)s * FD + f];
    }
    __shared__ float lds[2 * FD];
    lds[y * FD + f] = acc;
    __syncthreads();
    if (y == 0) {
        float v = lds[f] + lds[FD + f];
        if (v != 0.f) unsafeAtomicAdd(&out[(long)HUB * FD + f], v * dinv[HUB]);
    }
}

// ---------------------------------------------------------------------------
// K7: out[N,96] = A[N,96] @ W[96,96] + bias (optional relu).
// Block (24,8) = 192 thr: thread owns cols 4c..4c+3 (one b128 W read per k)
// and rows y+8j. A tile 64 rows in LDS (stride 100 pad).
// SAFE IN-PLACE (out may == A): each block stages its full 64-row tile into
// LDS behind __syncthreads before any write, and blocks only write their own
// tile's rows (A-reads are tile-local).
// ---------------------------------------------------------------------------
__global__ __launch_bounds__(192)
void gemm96(const float* __restrict__ A, const float* __restrict__ W,
            const float* __restrict__ bias, float* __restrict__ out,
            int N, int relu) {
    __shared__ float Wl[FD * FD];        // 36864 B
    __shared__ float As[64 * 100];       // 25600 B
    int t = threadIdx.y * 24 + threadIdx.x;   // 0..191

    {   // stage W (row-major, float4)
        const float4* W4 = (const float4*)W;
        float4* Wl4 = (float4*)Wl;
        #pragma unroll 4
        for (int i = t; i < FD * 24; i += 192) Wl4[i] = W4[i];
    }
    int row0 = blockIdx.x * 64;
    int nrows = min(64, N - row0);
    {   // stage A tile with pad-100 layout
        const float4* A4 = (const float4*)(A + (long)row0 * FD);
        for (int i = t; i < nrows * 24; i += 192) {
            int r = i / 24, g = i % 24;
            *(float4*)&As[r * 100 + g * 4] = A4[i];
        }
    }
    __syncthreads();

    int c = threadIdx.x;   // 0..23
    int y = threadIdx.y;   // 0..7
    float acc[8][4];
    #pragma unroll
    for (int j = 0; j < 8; j++)
        #pragma unroll
        for (int i = 0; i < 4; i++) acc[j][i] = 0.f;

    for (int kk = 0; kk < FD; kk += 4) {
        float4 w0 = *(const float4*)&Wl[(kk + 0) * FD + 4 * c];
        float4 w1 = *(const float4*)&Wl[(kk + 1) * FD + 4 * c];
        float4 w2 = *(const float4*)&Wl[(kk + 2) * FD + 4 * c];
        float4 w3 = *(const float4*)&Wl[(kk + 3) * FD + 4 * c];
        #pragma unroll
        for (int j = 0; j < 8; j++) {
            float4 a = *(const float4*)&As[(y + 8 * j) * 100 + kk];
            acc[j][0] = fmaf(a.x, w0.x, fmaf(a.y, w1.x, fmaf(a.z, w2.x, fmaf(a.w, w3.x, acc[j][0]))));
            acc[j][1] = fmaf(a.x, w0.y, fmaf(a.y, w1.y, fmaf(a.z, w2.y, fmaf(a.w, w3.y, acc[j][1]))));
            acc[j][2] = fmaf(a.x, w0.z, fmaf(a.y, w1.z, fmaf(a.z, w2.z, fmaf(a.w, w3.z, acc[j][2]))));
            acc[j][3] = fmaf(a.x, w0.w, fmaf(a.y, w1.w, fmaf(a.z, w2.w, fmaf(a.w, w3.w, acc[j][3]))));
        }
    }

    float4 b4 = *(const float4*)&bias[4 * c];
    #pragma unroll
    for (int j = 0; j < 8; j++) {
        int r = y + 8 * j;
        if (r < nrows) {
            float4 v;
            v.x = acc[j][0] + b4.x; v.y = acc[j][1] + b4.y;
            v.z = acc[j][2] + b4.z; v.w = acc[j][3] + b4.w;
            if (relu) {
                v.x = fmaxf(v.x, 0.f); v.y = fmaxf(v.y, 0.f);
                v.z = fmaxf(v.z, 0.f); v.w = fmaxf(v.w, 0.f);
            }
            *(float4*)&out[(long)(row0 + r) * FD + 4 * c] = v;
        }
    }
}

// ---------------------------------------------------------------------------
// Launch. (A@X)@W == A@(X@W) reassociation shares the aggregation.
// Liveness-based aliasing keeps ALL N*96 temporaries inside d_out
// (ws holds only CSR + small arrays, ~4.4 MB):
//   a0 = A@x            -> ls slot
//   h1 = relu(a0@W1+b1) -> mu slot
//   a1 = A@h1           -> ls slot   (a0 dead)
//   mu = a1@W2a+b2a     -> mu slot   (h1 dead)
//   ls = a1@W2b+b2b     -> ls slot   (IN-PLACE over a1; gemm96 is tile-local)
// ---------------------------------------------------------------------------
extern "C" void kernel_launch(void* const* d_in, const int* in_sizes, int n_in,
                              void* d_out, int out_size, void* d_ws, size_t ws_size,
                              hipStream_t stream) {
    const float* x   = (const float*)d_in[0];
    const float* W1  = (const float*)d_in[1];
    const float* b1  = (const float*)d_in[2];
    const float* W2a = (const float*)d_in[3];
    const float* b2a = (const float*)d_in[4];
    const float* W2b = (const float*)d_in[5];
    const float* b2b = (const float*)d_in[6];
    const int*   ei  = (const int*)d_in[7];

    const int N   = in_sizes[0] / FD;
    const int E   = in_sizes[7] / 2;
    const int HUB = N - 1;
    const int* src = ei;
    const int* dst = ei + E;

    // ws layout: [counts N][cursor N][rowptr N+1][col E][dinv N]  (~4.4 MB)
    int* counts = (int*)d_ws;
    int* cursor = counts + N;
    int* rowptr = cursor + N;
    int* col    = rowptr + (N + 1);
    float* dinv = (float*)(col + E);

    float* mu = (float*)d_out;
    float* ls = (float*)d_out + (size_t)N * FD;
    float* a0 = ls;    // lives until gemm1 consumes it
    float* h1 = mu;    // lives until pull/hub layer-2 consume it
    float* a1 = ls;    // overwrites dead a0

    // zero counts + cursor (contiguous, 2N ints)
    hipMemsetAsync(counts, 0, (size_t)2 * N * sizeof(int), stream);

    // CSR build (reused by both aggregation layers)
    deg_kernel <<<dim3((E + 255) / 256), dim3(256), 0, stream>>>(dst, E, HUB, counts);
    scan_kernel<<<dim3(1), dim3(1024), 0, stream>>>(counts, rowptr, N);
    fill_kernel<<<dim3((E + 255) / 256), dim3(256), 0, stream>>>(src, dst, E, HUB,
                                                                 rowptr, cursor, col);
    dinv_kernel<<<dim3((N + 255) / 256), dim3(256), 0, stream>>>(counts, dinv, N);

    dim3 pullB(FD, 4);
    int  pullG = (N + 3) / 4;
    dim3 hubB(FD, 2);
    int  hubG = 128;
    int  gemmG = (N + 63) / 64;
    dim3 gemmB(24, 8);

    // layer 1
    pull_kernel<<<dim3(pullG), pullB, 0, stream>>>(x, dinv, rowptr, col, N, HUB, a0);
    hub_kernel <<<dim3(hubG),  hubB, 0, stream>>>(x, dinv, rowptr, col, HUB, a0);
    gemm96     <<<dim3(gemmG), gemmB, 0, stream>>>(a0, W1, b1, h1, N, 1);

    // layer 2 (aggregation shared by mu and logstd)
    pull_kernel<<<dim3(pullG), pullB, 0, stream>>>(h1, dinv, rowptr, col, N, HUB, a1);
    hub_kernel <<<dim3(hubG),  hubB, 0, stream>>>(h1, dinv, rowptr, col, HUB, a1);
    gemm96     <<<dim3(gemmG), gemmB, 0, stream>>>(a1, W2a, b2a, mu, N, 0);
    gemm96     <<<dim3(gemmG), gemmB, 0, stream>>>(a1, W2b, b2b, ls, N, 0);  // in-place
}

// Round 5
// 467.561 us; speedup vs baseline: 1.7796x; 1.5966x over previous
//
#include <hip/hip_runtime.h>

#define FD 96   // feature dim

// ---------------------------------------------------------------------------
// K1: degree histogram (int counts). Hub handled via ballot+popcount to avoid
// ~50k serialized atomics on one address.
// ---------------------------------------------------------------------------
__global__ void deg_kernel(const int* __restrict__ dst, int E, int HUB,
                           int* __restrict__ counts) {
    int e = blockIdx.x * 256 + threadIdx.x;
    int d = (e < E) ? dst[e] : -1;
    bool isHub = (d == HUB);
    unsigned long long m = __ballot(isHub);
    if (isHub) {
        int lane = threadIdx.x & 63;
        if (lane == __ffsll((unsigned long long)m) - 1)
            atomicAdd(&counts[HUB], (int)__popcll(m));
    } else if (d >= 0) {
        atomicAdd(&counts[d], 1);
    }
}

// ---------------------------------------------------------------------------
// K2: exclusive prefix sum of counts -> rowptr[N+1]. Single block, 1024
// threads, wave-shuffle scan + cross-wave LDS.
// ---------------------------------------------------------------------------
__global__ __launch_bounds__(1024)
void scan_kernel(const int* __restrict__ counts, int* __restrict__ rowptr, int N) {
    const int T = 1024;
    int lane = threadIdx.x & 63;
    int wv   = threadIdx.x >> 6;      // 0..15
    __shared__ int wsum[16];
    __shared__ int carry_s;
    if (threadIdx.x == 0) carry_s = 0;
    __syncthreads();
    for (int base = 0; base < N; base += T) {
        int i = base + threadIdx.x;
        int v = (i < N) ? counts[i] : 0;
        int x = v;
        #pragma unroll
        for (int off = 1; off < 64; off <<= 1) {
            int t = __shfl_up(x, off);
            if (lane >= off) x += t;
        }
        if (lane == 63) wsum[wv] = x;
        __syncthreads();
        if (wv == 0 && lane < 16) {
            int w = wsum[lane];
            #pragma unroll
            for (int off = 1; off < 16; off <<= 1) {
                int t = __shfl_up(w, off);
                if (lane >= off) w += t;
            }
            wsum[lane] = w;                    // inclusive wave sums
        }
        __syncthreads();
        int waveoff = (wv == 0) ? 0 : wsum[wv - 1];
        int carry = carry_s;
        int incl = carry + waveoff + x;
        if (i < N) rowptr[i] = incl - v;       // exclusive
        __syncthreads();
        if (threadIdx.x == T - 1) carry_s = incl;
        __syncthreads();
    }
    if (threadIdx.x == 0) rowptr[N] = carry_s;
}

// ---------------------------------------------------------------------------
// K3: fill CSR col[] (src ids per dst row). Hub cursor via wave-aggregated
// atomic (one atomicAdd of popcount per wave) to avoid serialization.
// ---------------------------------------------------------------------------
__global__ void fill_kernel(const int* __restrict__ src, const int* __restrict__ dst,
                            int E, int HUB, const int* __restrict__ rowptr,
                            int* __restrict__ cursor, int* __restrict__ col) {
    int e = blockIdx.x * 256 + threadIdx.x;
    if (e >= E) return;
    int d = dst[e];
    bool isHub = (d == HUB);
    unsigned long long m = __ballot(isHub);
    int pos;
    if (isHub) {
        int lane = threadIdx.x & 63;
        int leader = __ffsll((unsigned long long)m) - 1;
        int base = 0;
        if (lane == leader) base = atomicAdd(&cursor[HUB], (int)__popcll(m));
        base = __shfl(base, leader);
        unsigned long long below = m & ((1ull << lane) - 1ull);
        pos = base + (int)__popcll(below);
    } else {
        pos = atomicAdd(&cursor[d], 1);
    }
    col[rowptr[d] + pos] = src[e];
}

// ---------------------------------------------------------------------------
// K4: dinv from int counts
// ---------------------------------------------------------------------------
__global__ void dinv_kernel(const int* __restrict__ counts, float* __restrict__ dinv,
                            int N) {
    int n = blockIdx.x * 256 + threadIdx.x;
    if (n < N) {
        float d = (float)counts[n];
        dinv[n] = (d > 0.f) ? rsqrtf(fmaxf(d, 1.f)) : 0.f;
    }
}

// ---------------------------------------------------------------------------
// K5: pull aggregation (light rows), latency-optimized:
// block (24,16): thread = (float4 feature chunk c, row y). Edge loop unrolled
// 8-deep -> 8 col + 8 dinv + 8 h4 gathers in flight per thread (MLP), vs the
// R4 version's serial 1-edge chase. Pure writes, no atomics.
// ---------------------------------------------------------------------------
__global__ __launch_bounds__(384)
void pull_kernel(const float* __restrict__ h, const float* __restrict__ dinv,
                 const int* __restrict__ rowptr, const int* __restrict__ col,
                 int N, int HUB, float* __restrict__ out) {
    int c = threadIdx.x;                       // 0..23
    int n = blockIdx.x * 16 + threadIdx.y;
    if (n >= N) return;
    const float4* h4 = (const float4*)h;
    float4* out4 = (float4*)out;
    long ob = (long)n * 24 + c;
    if (n == HUB) { out4[ob] = make_float4(0.f, 0.f, 0.f, 0.f); return; }
    int beg = rowptr[n], end = rowptr[n + 1];
    float dn = dinv[n];
    float ax = 0.f, ay = 0.f, az = 0.f, aw = 0.f;
    int e = beg;
    for (; e + 8 <= end; e += 8) {
        int s0 = col[e + 0], s1 = col[e + 1], s2 = col[e + 2], s3 = col[e + 3];
        int s4 = col[e + 4], s5 = col[e + 5], s6 = col[e + 6], s7 = col[e + 7];
        float w0 = dinv[s0], w1 = dinv[s1], w2 = dinv[s2], w3 = dinv[s3];
        float w4 = dinv[s4], w5 = dinv[s5], w6 = dinv[s6], w7 = dinv[s7];
        float4 v0 = h4[(long)s0 * 24 + c], v1 = h4[(long)s1 * 24 + c];
        float4 v2 = h4[(long)s2 * 24 + c], v3 = h4[(long)s3 * 24 + c];
        float4 v4 = h4[(long)s4 * 24 + c], v5 = h4[(long)s5 * 24 + c];
        float4 v6 = h4[(long)s6 * 24 + c], v7 = h4[(long)s7 * 24 + c];
        ax = fmaf(w0, v0.x, fmaf(w1, v1.x, fmaf(w2, v2.x, fmaf(w3, v3.x,
             fmaf(w4, v4.x, fmaf(w5, v5.x, fmaf(w6, v6.x, fmaf(w7, v7.x, ax))))))));
        ay = fmaf(w0, v0.y, fmaf(w1, v1.y, fmaf(w2, v2.y, fmaf(w3, v3.y,
             fmaf(w4, v4.y, fmaf(w5, v5.y, fmaf(w6, v6.y, fmaf(w7, v7.y, ay))))))));
        az = fmaf(w0, v0.z, fmaf(w1, v1.z, fmaf(w2, v2.z, fmaf(w3, v3.z,
             fmaf(w4, v4.z, fmaf(w5, v5.z, fmaf(w6, v6.z, fmaf(w7, v7.z, az))))))));
        aw = fmaf(w0, v0.w, fmaf(w1, v1.w, fmaf(w2, v2.w, fmaf(w3, v3.w,
             fmaf(w4, v4.w, fmaf(w5, v5.w, fmaf(w6, v6.w, fmaf(w7, v7.w, aw))))))));
    }
    for (; e < end; e++) {
        int s = col[e];
        float w = dinv[s];
        float4 v = h4[(long)s * 24 + c];
        ax = fmaf(w, v.x, ax); ay = fmaf(w, v.y, ay);
        az = fmaf(w, v.z, az); aw = fmaf(w, v.w, aw);
    }
    out4[ob] = make_float4(ax * dn, ay * dn, az * dn, aw * dn);
}

// ---------------------------------------------------------------------------
// K6: hub row (deg ~50016): 2048 contiguous edge chunks (256 blocks x 8),
// float4 lanes, 4-deep unroll for MLP, LDS reduce, 96 atomics/block into the
// (pre-zeroed) hub row.
// ---------------------------------------------------------------------------
__global__ __launch_bounds__(192)
void hub_kernel(const float* __restrict__ h, const float* __restrict__ dinv,
                const int* __restrict__ rowptr, const int* __restrict__ col,
                int HUB, float* __restrict__ out) {
    int c = threadIdx.x;   // 0..23
    int y = threadIdx.y;   // 0..7
    const float4* h4 = (const float4*)h;
    int beg = rowptr[HUB], end = rowptr[HUB + 1];
    int deg = end - beg;
    int nstr = gridDim.x * 8;
    int sid  = blockIdx.x * 8 + y;
    int chunk = (deg + nstr - 1) / nstr;
    int e  = beg + sid * chunk;
    int e1 = min(e + chunk, end);
    float ax = 0.f, ay = 0.f, az = 0.f, aw = 0.f;
    for (; e + 4 <= e1; e += 4) {
        int s0 = col[e + 0], s1 = col[e + 1], s2 = col[e + 2], s3 = col[e + 3];
        float w0 = dinv[s0], w1 = dinv[s1], w2 = dinv[s2], w3 = dinv[s3];
        float4 v0 = h4[(long)s0 * 24 + c], v1 = h4[(long)s1 * 24 + c];
        float4 v2 = h4[(long)s2 * 24 + c], v3 = h4[(long)s3 * 24 + c];
        ax = fmaf(w0, v0.x, fmaf(w1, v1.x, fmaf(w2, v2.x, fmaf(w3, v3.x, ax))));
        ay = fmaf(w0, v0.y, fmaf(w1, v1.y, fmaf(w2, v2.y, fmaf(w3, v3.y, ay))));
        az = fmaf(w0, v0.z, fmaf(w1, v1.z, fmaf(w2, v2.z, fmaf(w3, v3.z, az))));
        aw = fmaf(w0, v0.w, fmaf(w1, v1.w, fmaf(w2, v2.w, fmaf(w3, v3.w, aw))));
    }
    for (; e < e1; e++) {
        int s = col[e];
        float w = dinv[s];
        float4 v = h4[(long)s * 24 + c];
        ax = fmaf(w, v.x, ax); ay = fmaf(w, v.y, ay);
        az = fmaf(w, v.z, az); aw = fmaf(w, v.w, aw);
    }
    __shared__ float4 red[8][24];
    red[y][c] = make_float4(ax, ay, az, aw);
    __syncthreads();
    if (y == 0) {
        float4 t = red[0][c];
        #pragma unroll
        for (int k = 1; k < 8; k++) {
            float4 u = red[k][c];
            t.x += u.x; t.y += u.y; t.z += u.z; t.w += u.w;
        }
        float dh = dinv[HUB];
        float* o = &out[(long)HUB * FD + 4 * c];
        unsafeAtomicAdd(o + 0, t.x * dh);
        unsafeAtomicAdd(o + 1, t.y * dh);
        unsafeAtomicAdd(o + 2, t.z * dh);
        unsafeAtomicAdd(o + 3, t.w * dh);
    }
}

// ---------------------------------------------------------------------------
// K7: out[N,96] = A[N,96] @ W[96,96] + bias (optional relu).
// Block (24,8): thread owns cols 4c..4c+3, rows y+8j. 64-row A tile in LDS
// (pad 100). SAFE IN-PLACE (out may == A): full tile staged behind
// __syncthreads before any write; blocks only touch their own tile rows.
// ---------------------------------------------------------------------------
__global__ __launch_bounds__(192)
void gemm96(const float* __restrict__ A, const float* __restrict__ W,
            const float* __restrict__ bias, float* __restrict__ out,
            int N, int relu) {
    __shared__ float Wl[FD * FD];        // 36864 B
    __shared__ float As[64 * 100];       // 25600 B
    int t = threadIdx.y * 24 + threadIdx.x;   // 0..191

    {   // stage W (row-major, float4)
        const float4* W4 = (const float4*)W;
        float4* Wl4 = (float4*)Wl;
        #pragma unroll 4
        for (int i = t; i < FD * 24; i += 192) Wl4[i] = W4[i];
    }
    int row0 = blockIdx.x * 64;
    int nrows = min(64, N - row0);
    {   // stage A tile with pad-100 layout
        const float4* A4 = (const float4*)(A + (long)row0 * FD);
        for (int i = t; i < nrows * 24; i += 192) {
            int r = i / 24, g = i % 24;
            *(float4*)&As[r * 100 + g * 4] = A4[i];
        }
    }
    __syncthreads();

    int c = threadIdx.x;   // 0..23
    int y = threadIdx.y;   // 0..7
    float acc[8][4];
    #pragma unroll
    for (int j = 0; j < 8; j++)
        #pragma unroll
        for (int i = 0; i < 4; i++) acc[j][i] = 0.f;

    for (int kk = 0; kk < FD; kk += 4) {
        float4 w0 = *(const float4*)&Wl[(kk + 0) * FD + 4 * c];
        float4 w1 = *(const float4*)&Wl[(kk + 1) * FD + 4 * c];
        float4 w2 = *(const float4*)&Wl[(kk + 2) * FD + 4 * c];
        float4 w3 = *(const float4*)&Wl[(kk + 3) * FD + 4 * c];
        #pragma unroll
        for (int j = 0; j < 8; j++) {
            float4 a = *(const float4*)&As[(y + 8 * j) * 100 + kk];
            acc[j][0] = fmaf(a.x, w0.x, fmaf(a.y, w1.x, fmaf(a.z, w2.x, fmaf(a.w, w3.x, acc[j][0]))));
            acc[j][1] = fmaf(a.x, w0.y, fmaf(a.y, w1.y, fmaf(a.z, w2.y, fmaf(a.w, w3.y, acc[j][1]))));
            acc[j][2] = fmaf(a.x, w0.z, fmaf(a.y, w1.z, fmaf(a.z, w2.z, fmaf(a.w, w3.z, acc[j][2]))));
            acc[j][3] = fmaf(a.x, w0.w, fmaf(a.y, w1.w, fmaf(a.z, w2.w, fmaf(a.w, w3.w, acc[j][3]))));
        }
    }

    float4 b4 = *(const float4*)&bias[4 * c];
    #pragma unroll
    for (int j = 0; j < 8; j++) {
        int r = y + 8 * j;
        if (r < nrows) {
            float4 v;
            v.x = acc[j][0] + b4.x; v.y = acc[j][1] + b4.y;
            v.z = acc[j][2] + b4.z; v.w = acc[j][3] + b4.w;
            if (relu) {
                v.x = fmaxf(v.x, 0.f); v.y = fmaxf(v.y, 0.f);
                v.z = fmaxf(v.z, 0.f); v.w = fmaxf(v.w, 0.f);
            }
            *(float4*)&out[(long)(row0 + r) * FD + 4 * c] = v;
        }
    }
}

// ---------------------------------------------------------------------------
// Launch. (A@X)@W == A@(X@W) reassociation shares the aggregation.
// All N*96 temporaries live inside d_out via liveness aliasing (ws ~4.4 MB):
//   a0 = A@x            -> ls slot
//   h1 = relu(a0@W1+b1) -> mu slot
//   a1 = A@h1           -> ls slot   (a0 dead)
//   mu = a1@W2a+b2a     -> mu slot   (h1 dead)
//   ls = a1@W2b+b2b     -> ls slot   (in-place; gemm96 is tile-local)
// ---------------------------------------------------------------------------
extern "C" void kernel_launch(void* const* d_in, const int* in_sizes, int n_in,
                              void* d_out, int out_size, void* d_ws, size_t ws_size,
                              hipStream_t stream) {
    const float* x   = (const float*)d_in[0];
    const float* W1  = (const float*)d_in[1];
    const float* b1  = (const float*)d_in[2];
    const float* W2a = (const float*)d_in[3];
    const float* b2a = (const float*)d_in[4];
    const float* W2b = (const float*)d_in[5];
    const float* b2b = (const float*)d_in[6];
    const int*   ei  = (const int*)d_in[7];

    const int N   = in_sizes[0] / FD;
    const int E   = in_sizes[7] / 2;
    const int HUB = N - 1;
    const int* src = ei;
    const int* dst = ei + E;

    // ws layout: [counts N][cursor N][rowptr N+1][col E][dinv N]  (~4.4 MB)
    int* counts = (int*)d_ws;
    int* cursor = counts + N;
    int* rowptr = cursor + N;
    int* col    = rowptr + (N + 1);
    float* dinv = (float*)(col + E);

    float* mu = (float*)d_out;
    float* ls = (float*)d_out + (size_t)N * FD;
    float* a0 = ls;
    float* h1 = mu;
    float* a1 = ls;

    hipMemsetAsync(counts, 0, (size_t)2 * N * sizeof(int), stream);

    // CSR build (reused by both aggregation layers)
    deg_kernel <<<dim3((E + 255) / 256), dim3(256), 0, stream>>>(dst, E, HUB, counts);
    scan_kernel<<<dim3(1), dim3(1024), 0, stream>>>(counts, rowptr, N);
    fill_kernel<<<dim3((E + 255) / 256), dim3(256), 0, stream>>>(src, dst, E, HUB,
                                                                 rowptr, cursor, col);
    dinv_kernel<<<dim3((N + 255) / 256), dim3(256), 0, stream>>>(counts, dinv, N);

    dim3 pullB(24, 16);
    int  pullG = (N + 15) / 16;
    dim3 hubB(24, 8);
    int  hubG = 256;
    int  gemmG = (N + 63) / 64;
    dim3 gemmB(24, 8);

    // layer 1
    pull_kernel<<<dim3(pullG), pullB, 0, stream>>>(x, dinv, rowptr, col, N, HUB, a0);
    hub_kernel <<<dim3(hubG),  hubB, 0, stream>>>(x, dinv, rowptr, col, HUB, a0);
    gemm96     <<<dim3(gemmG), gemmB, 0, stream>>>(a0, W1, b1, h1, N, 1);

    // layer 2 (aggregation shared by mu and logstd)
    pull_kernel<<<dim3(pullG), pullB, 0, stream>>>(h1, dinv, rowptr, col, N, HUB, a1);
    hub_kernel <<<dim3(hubG),  hubB, 0, stream>>>(h1, dinv, rowptr, col, HUB, a1);
    gemm96     <<<dim3(gemmG), gemmB, 0, stream>>>(a1, W2a, b2a, mu, N, 0);
    gemm96     <<<dim3(gemmG), gemmB, 0, stream>>>(a1, W2b, b2b, ls, N, 0);  // in-place
}